// Round 8
// baseline (161.881 us; speedup 1.0000x reference)
//
#include <hip/hip_runtime.h>
#include <hip/hip_bf16.h>

// ---------------------------------------------------------------------------
// ContrastiveLoss: B=8192, D=64, fp32 inputs, scalar fp32 output.
// Structure = R3 (measured best, 98.3us): 3 kernels, unique-writer partials.
// R8 change: score processes PAIRED column-tiles (32 cols/iter) with the B
// fragments of the NEXT pair prefetched 2 tiles ahead -> ~4x latency coverage
// vs R3's depth-1 (tests the dependent-chain-exposure theory; R6 more-waves
// and R7 LDS-staging both falsified their theories, dur invariant ~100us).
//   1) norm: fused |x|^2,|t|^2,x.t butterfly; bf16 copies (imgB pre-scaled
//      by K1 = LOG2E/T); exact fp32 diagonal; zeroes d_out.
//   2) score: 1024 blocks; wave = 64 rows x 256 cols; MFMA C-init = -K1 so
//      acc IS the exp2 argument; row/col partials, unique-writer stores.
//   3) finish: reduce 32 row- + 128 col-partials -> logsumexp -> focal loss.
// No max pass needed: unit vectors => |s| <= 1/T; fixed shift M = 1/T keeps
// exp(s-M) in [e^-28.6, 1] (fp32-safe).
// ---------------------------------------------------------------------------

#define NB 8192
#define ND 64

constexpr float INV_T = 1.0f / 0.07f;                 // 14.2857...
constexpr float LOG2E = 1.4426950408889634f;
constexpr float LN2   = 0.6931471805599453f;
constexpr float K1    = INV_T * LOG2E;                // exp2 arg scale

typedef float  floatx4 __attribute__((ext_vector_type(4)));
typedef short  bf16x8  __attribute__((ext_vector_type(8)));

// --------------------------- kernel 1: normalize ---------------------------
__global__ __launch_bounds__(256)
void norm_kernel(const float* __restrict__ img, const float* __restrict__ txt,
                 __hip_bfloat16* __restrict__ imgB,
                 __hip_bfloat16* __restrict__ txtB,
                 float* __restrict__ diag,
                 float* __restrict__ out)
{
    if (blockIdx.x == 0 && threadIdx.x == 0) out[0] = 0.f;
    const int lane = threadIdx.x & 63;
    const int row  = blockIdx.x * 4 + (threadIdx.x >> 6);
    const float x = img[row * ND + lane];
    const float t = txt[row * ND + lane];
    float sx = x * x, st = t * t, sxt = x * t;
    #pragma unroll
    for (int o = 1; o < 64; o <<= 1) {
        sx  += __shfl_xor(sx,  o, 64);
        st  += __shfl_xor(st,  o, 64);
        sxt += __shfl_xor(sxt, o, 64);
    }
    const float nx_den = fmaxf(sqrtf(sx), 1e-12f);
    const float nt_den = fmaxf(sqrtf(st), 1e-12f);
    imgB[row * ND + lane] = __float2bfloat16(x / nx_den * K1);  // A pre-scaled
    txtB[row * ND + lane] = __float2bfloat16(t / nt_den);
    if (lane == 0) diag[row] = sxt / (nx_den * nt_den) * INV_T;
}

// ----------------------- kernel 2: streamed score pass ---------------------
// 1024 blocks x 4 waves: strip = gw>>5 (64 rows), chunk = gw&31 (256 cols =
// 16 tiles of 16, processed as 8 PAIRS). B fragments for pair u+1 issued
// while pair u computes (branchless wraparound).
// mfma_f32_16x16x32_bf16 layouts (HW-verified):
//   A: lane holds A[m=lane&15][k=(lane>>4)*8 + j], j=0..7  (8 contig bf16)
//   B: lane holds B[n=lane&15][k=(lane>>4)*8 + j]          (NT layout)
//   C/D: col = lane&15, row = (lane>>4)*4 + r
__global__ __launch_bounds__(256, 4)
void score_kernel(const __hip_bfloat16* __restrict__ imgB,
                  const __hip_bfloat16* __restrict__ txtB,
                  float* __restrict__ rowPart,   // [32][8192]
                  float* __restrict__ colPart)   // [128][8192]
{
    const int wid   = threadIdx.x >> 6;
    const int lane  = threadIdx.x & 63;
    const int gw    = blockIdx.x * 4 + wid;   // 0..4095
    const int strip = gw >> 5;                // rows strip*64..+63
    const int chunk = gw & 31;                // cols chunk*256..+255
    const int m = lane & 15;
    const int q = lane >> 4;

    const bf16x8* __restrict__ A  = (const bf16x8*)imgB;  // units of 8 elems
    const bf16x8* __restrict__ Bp = (const bf16x8*)txtB;

    const int rowbase = strip * 64;
    bf16x8 a[4][2];
    #pragma unroll
    for (int it = 0; it < 4; ++it) {
        const int r = rowbase + it * 16 + m;
        a[it][0] = A[r * 8 + q];        // k = q*8 .. q*8+7
        a[it][1] = A[r * 8 + 4 + q];    // k = 32 + q*8 ..
    }

    const int colbase = chunk * 256 + m;      // this lane's tile-0 column

    // prime: B fragments for tiles 0 and 1
    bf16x8 b00 = Bp[(colbase      ) * 8 + q];
    bf16x8 b01 = Bp[(colbase      ) * 8 + 4 + q];
    bf16x8 b10 = Bp[(colbase + 16 ) * 8 + q];
    bf16x8 b11 = Bp[(colbase + 16 ) * 8 + 4 + q];

    float rs[16];
    #pragma unroll
    for (int i = 0; i < 16; ++i) rs[i] = 0.f;

    const floatx4 NEGK = {-K1, -K1, -K1, -K1};   // bakes the -M shift in

    #pragma unroll
    for (int u = 0; u < 8; ++u) {
        // prefetch the NEXT pair (tiles 2u+2, 2u+3; wraps at the end: harmless)
        const int n2 = colbase + (((2 * u + 2) & 15) << 4);
        const int n3 = colbase + (((2 * u + 3) & 15) << 4);
        const bf16x8 p00 = Bp[n2 * 8 + q];
        const bf16x8 p01 = Bp[n2 * 8 + 4 + q];
        const bf16x8 p10 = Bp[n3 * 8 + q];
        const bf16x8 p11 = Bp[n3 * 8 + 4 + q];

        // ---- tile 2u ----
        {
            float csp[4];
            #pragma unroll
            for (int it = 0; it < 4; ++it) {
                floatx4 z   = __builtin_amdgcn_mfma_f32_16x16x32_bf16(a[it][0], b00, NEGK, 0, 0, 0);
                floatx4 acc = __builtin_amdgcn_mfma_f32_16x16x32_bf16(a[it][1], b01, z,    0, 0, 0);
                const float e0 = __builtin_amdgcn_exp2f(acc[0]);
                const float e1 = __builtin_amdgcn_exp2f(acc[1]);
                const float e2 = __builtin_amdgcn_exp2f(acc[2]);
                const float e3 = __builtin_amdgcn_exp2f(acc[3]);
                rs[it * 4 + 0] += e0;
                rs[it * 4 + 1] += e1;
                rs[it * 4 + 2] += e2;
                rs[it * 4 + 3] += e3;
                csp[it] = (e0 + e1) + (e2 + e3);
            }
            float cs = (csp[0] + csp[1]) + (csp[2] + csp[3]);
            cs += __shfl_xor(cs, 16, 64);
            cs += __shfl_xor(cs, 32, 64);
            if (q == 0) colPart[strip * NB + colbase + (2 * u) * 16] = cs;  // unique writer
        }
        // ---- tile 2u+1 ----
        {
            float csp[4];
            #pragma unroll
            for (int it = 0; it < 4; ++it) {
                floatx4 z   = __builtin_amdgcn_mfma_f32_16x16x32_bf16(a[it][0], b10, NEGK, 0, 0, 0);
                floatx4 acc = __builtin_amdgcn_mfma_f32_16x16x32_bf16(a[it][1], b11, z,    0, 0, 0);
                const float e0 = __builtin_amdgcn_exp2f(acc[0]);
                const float e1 = __builtin_amdgcn_exp2f(acc[1]);
                const float e2 = __builtin_amdgcn_exp2f(acc[2]);
                const float e3 = __builtin_amdgcn_exp2f(acc[3]);
                rs[it * 4 + 0] += e0;
                rs[it * 4 + 1] += e1;
                rs[it * 4 + 2] += e2;
                rs[it * 4 + 3] += e3;
                csp[it] = (e0 + e1) + (e2 + e3);
            }
            float cs = (csp[0] + csp[1]) + (csp[2] + csp[3]);
            cs += __shfl_xor(cs, 16, 64);
            cs += __shfl_xor(cs, 32, 64);
            if (q == 0) colPart[strip * NB + colbase + (2 * u + 1) * 16] = cs;  // unique writer
        }
        b00 = p00; b01 = p01; b10 = p10; b11 = p11;
    }

    // flush row sums: reduce each rs[idx] across the 16 lanes of the quad
    #pragma unroll
    for (int idx = 0; idx < 16; ++idx) {
        float v = rs[idx];
        v += __shfl_xor(v, 1, 64);
        v += __shfl_xor(v, 2, 64);
        v += __shfl_xor(v, 4, 64);
        v += __shfl_xor(v, 8, 64);
        if (m == idx) {
            const int it = idx >> 2, r = idx & 3;
            rowPart[chunk * NB + rowbase + it * 16 + q * 4 + r] = v;  // unique writer
        }
    }
}

// --------------------------- kernel 3: finish ------------------------------
__global__ __launch_bounds__(256)
void finish_kernel(const float* __restrict__ rowPart,
                   const float* __restrict__ colPart,
                   const float* __restrict__ diag,
                   float* __restrict__ out)
{
    const int i = blockIdx.x * 256 + threadIdx.x;   // 0..8191
    float rowS = 0.f, colS = 0.f;
    #pragma unroll 4
    for (int c = 0; c < 32; ++c)  rowS += rowPart[c * NB + i];
    #pragma unroll 4
    for (int s = 0; s < 128; ++s) colS += colPart[s * NB + i];
    const float d     = diag[i];
    const float lse_r = INV_T + __builtin_amdgcn_logf(rowS) * LN2;
    const float lse_c = INV_T + __builtin_amdgcn_logf(colS) * LN2;
    const float lpr = d - lse_r;
    const float lpc = d - lse_c;
    const float p   = __builtin_amdgcn_exp2f(lpr * LOG2E);
    const float om  = 1.f - p;
    float contrib = om * om * (-lpr - lpc) * (0.5f / (float)NB);

    #pragma unroll
    for (int o = 1; o < 64; o <<= 1) contrib += __shfl_xor(contrib, o, 64);
    __shared__ float red[4];
    if ((threadIdx.x & 63) == 0) red[threadIdx.x >> 6] = contrib;
    __syncthreads();
    if (threadIdx.x == 0)
        atomicAdd(out, red[0] + red[1] + red[2] + red[3]);
}

// ---------------------------------------------------------------------------
extern "C" void kernel_launch(void* const* d_in, const int* in_sizes, int n_in,
                              void* d_out, int out_size, void* d_ws, size_t ws_size,
                              hipStream_t stream)
{
    const float* img = (const float*)d_in[0];
    const float* txt = (const float*)d_in[1];

    char* ws = (char*)d_ws;
    __hip_bfloat16* imgB = (__hip_bfloat16*)(ws);                        // 1 MB
    __hip_bfloat16* txtB = (__hip_bfloat16*)(ws + (1u << 20));           // 1 MB
    float* diag    = (float*)(ws + (2u << 20));                          // 32 KB
    float* rowPart = (float*)(ws + (2u << 20) + (1u << 16));             // 1 MB
    float* colPart = (float*)(ws + (3u << 20) + (1u << 16));             // 4 MB

    norm_kernel<<<NB / 4, 256, 0, stream>>>(img, txt, imgB, txtB, diag, (float*)d_out);
    score_kernel<<<1024, 256, 0, stream>>>(imgB, txtB, rowPart, colPart);
    finish_kernel<<<NB / 256, 256, 0, stream>>>(rowPart, colPart, diag, (float*)d_out);
}